// Round 1
// baseline (26.773 us; speedup 1.0000x reference)
//
#include <hip/hip_runtime.h>
#include <math.h>

#define HDIM 32
#define NSTEPS 32
#define NSECANT 8
#define RADIUSV 1.0f
#define NEARV 0.5f
#define TAUV 0.5f
#define EPSV 1e-6f

__global__ __launch_bounds__(256) void unisurf_kernel(
    const float* __restrict__ cam_loc,   // [3]
    const float* __restrict__ ray_dirs,  // [P*3]
    const float* __restrict__ W1,        // [3*HDIM] row-major (3 rows of HDIM)
    const float* __restrict__ b1,        // [HDIM]
    const float* __restrict__ W2,        // [HDIM]
    const float* __restrict__ b2,        // [1]
    float* __restrict__ out,             // [2*P]: d_pred then occ_surf
    int P)
{
    __shared__ float4 sW[HDIM];   // (w0, w1, w2, b1) per hidden unit
    __shared__ float  sW2[HDIM];
    __shared__ float  sB2;

    const int tid = threadIdx.x;
    if (tid < HDIM) {
        sW[tid] = make_float4(W1[tid], W1[HDIM + tid], W1[2 * HDIM + tid], b1[tid]);
        sW2[tid] = W2[tid];
    }
    if (tid == 0) sB2 = b2[0];
    __syncthreads();

    const int i = blockIdx.x * blockDim.x + tid;
    if (i >= P) return;

    // camera (wave-uniform)
    const float cx = cam_loc[0], cy = cam_loc[1], cz = cam_loc[2];

    // ray load + normalize
    float dx = ray_dirs[3 * i + 0];
    float dy = ray_dirs[3 * i + 1];
    float dz = ray_dirs[3 * i + 2];
    float nrm = sqrtf(dx * dx + dy * dy + dz * dz);
    float rx = dx / nrm, ry = dy / nrm, rz = dz / nrm;

    // sphere intersection
    float rcd = rx * cx + ry * cy + rz * cz;
    float c2  = cx * cx + cy * cy + cz * cz;
    float us  = rcd * rcd - (c2 - RADIUSV * RADIUSV);
    bool  mask_int = us > 0.0f;
    float s_sq = mask_int ? sqrtf(us) : 0.0f;
    float far_raw = mask_int ? fmaxf(s_sq - rcd, 0.0f) : 0.0f;
    float farv = fmaxf(far_raw, NEARV + EPSV);

    // per-ray factored MLP weights:
    //   a_h(d) = cW[h] + d * rW[h];  logit = sum_h relu(a_h)*w2r[h] + B2
    float rW[HDIM], cW[HDIM], w2r[HDIM];
    #pragma unroll
    for (int h = 0; h < HDIM; ++h) {
        float4 w = sW[h];
        rW[h]  = rx * w.x + ry * w.y + rz * w.z;
        cW[h]  = cx * w.x + cy * w.y + cz * w.z + w.w;
        w2r[h] = sW2[h];
    }
    const float B2 = sB2;

    auto logit = [&](float d) -> float {
        float a0 = 0.0f, a1 = 0.0f, a2 = 0.0f, a3 = 0.0f;
        #pragma unroll
        for (int h = 0; h < HDIM; h += 4) {
            float x0 = fmaf(d, rW[h + 0], cW[h + 0]);
            float x1 = fmaf(d, rW[h + 1], cW[h + 1]);
            float x2 = fmaf(d, rW[h + 2], cW[h + 2]);
            float x3 = fmaf(d, rW[h + 3], cW[h + 3]);
            a0 = fmaf(fmaxf(x0, 0.0f), w2r[h + 0], a0);
            a1 = fmaf(fmaxf(x1, 0.0f), w2r[h + 1], a1);
            a2 = fmaf(fmaxf(x2, 0.0f), w2r[h + 2], a2);
            a3 = fmaf(fmaxf(x3, 0.0f), w2r[h + 3], a3);
        }
        return (a0 + a1) + (a2 + a3) + B2;
    };
    auto fval = [&](float d) -> float {   // occ(d) - TAU
        float x = logit(d);
        return 1.0f / (1.0f + expf(-x)) - TAUV;
    };

    // coarse march over d = NEAR*(1-t) + far*t, t = s/31
    float d_prev = NEARV;
    float f_prev = fval(NEARV);
    float f0 = f_prev;
    float d1v = 0.0f, f1v = 0.0f;

    bool found = false;
    float d_lo = 0.0f, f_lo = 0.0f, d_hi = 0.0f, f_hi = 0.0f;

    #pragma unroll 1
    for (int s = 1; s < NSTEPS; ++s) {
        float t = (float)s / 31.0f;
        float dd = NEARV * (1.0f - t) + farv * t;
        float fs = fval(dd);
        if (s == 1) { d1v = dd; f1v = fs; }
        if (!found && (f_prev < 0.0f) && (fs >= 0.0f)) {
            found = true;
            d_lo = d_prev; f_lo = f_prev;
            d_hi = dd;     f_hi = fs;
        }
        d_prev = dd; f_prev = fs;
    }
    if (!found) {  // reference: idx = argmax(all-false) = 0
        d_lo = NEARV; f_lo = f0;
        d_hi = d1v;   f_hi = f1v;
    }
    found = found && mask_int;

    // secant refinement
    #pragma unroll 1
    for (int it = 0; it < NSECANT; ++it) {
        float den = f_hi - f_lo;
        den = (fabsf(den) < EPSV) ? EPSV : den;
        float dm = d_lo - f_lo * (d_hi - d_lo) / den;
        float fm = fval(dm);
        bool neg = fm < 0.0f;
        d_lo = neg ? dm : d_lo;
        f_lo = neg ? fm : f_lo;
        d_hi = neg ? d_hi : dm;
        f_hi = neg ? f_hi : fm;
    }
    float den = f_hi - f_lo;
    den = (fabsf(den) < EPSV) ? EPSV : den;
    float d_mid = d_lo - f_lo * (d_hi - d_lo) / den;

    float d_pred = found ? d_mid : 0.0f;
    float occ_s = 1.0f / (1.0f + expf(-logit(d_pred)));
    float occ_surf = found ? occ_s : 0.0f;

    out[i]     = d_pred;
    out[P + i] = occ_surf;
}

extern "C" void kernel_launch(void* const* d_in, const int* in_sizes, int n_in,
                              void* d_out, int out_size, void* d_ws, size_t ws_size,
                              hipStream_t stream) {
    const float* cam_loc  = (const float*)d_in[0];
    const float* ray_dirs = (const float*)d_in[1];
    const float* W1       = (const float*)d_in[2];
    const float* b1       = (const float*)d_in[3];
    const float* W2       = (const float*)d_in[4];
    const float* b2       = (const float*)d_in[5];
    float* out = (float*)d_out;

    const int P = in_sizes[1] / 3;
    const int block = 256;
    const int grid = (P + block - 1) / block;
    unisurf_kernel<<<grid, block, 0, stream>>>(cam_loc, ray_dirs, W1, b1, W2, b2, out, P);
}

// Round 2
// 21.044 us; speedup vs baseline: 1.2722x; 1.2722x over previous
//
#include <hip/hip_runtime.h>
#include <math.h>

#define HDIM 32
#define NSTEPS 32
#define NSECANT 8
#define RADIUSV 1.0f
#define NEARV 0.5f
#define TAUV 0.5f
#define EPSV 1e-6f

typedef float f2 __attribute__((ext_vector_type(2)));

__global__ __launch_bounds__(256) void unisurf_kernel(
    const float* __restrict__ cam_loc,   // [3]
    const float* __restrict__ ray_dirs,  // [P*3]
    const float* __restrict__ W1,        // [3*HDIM] row-major (3 rows of HDIM)
    const float* __restrict__ b1,        // [HDIM]
    const float* __restrict__ W2,        // [HDIM]
    const float* __restrict__ b2,        // [1]
    float* __restrict__ out,             // [2*P]: d_pred then occ_surf
    int P)
{
    __shared__ float4 sW[HDIM];   // (w0, w1, w2, b1) per hidden unit
    __shared__ float  sW2[HDIM];
    __shared__ float  sB2;

    const int tid = threadIdx.x;
    if (tid < HDIM) {
        sW[tid] = make_float4(W1[tid], W1[HDIM + tid], W1[2 * HDIM + tid], b1[tid]);
        sW2[tid] = W2[tid];
    }
    if (tid == 0) sB2 = b2[0];
    __syncthreads();

    const int i = blockIdx.x * blockDim.x + tid;
    if (i >= P) return;

    // camera (wave-uniform)
    const float cx = cam_loc[0], cy = cam_loc[1], cz = cam_loc[2];

    // ray load + normalize (IEEE, once per ray — keep exact)
    float dx = ray_dirs[3 * i + 0];
    float dy = ray_dirs[3 * i + 1];
    float dz = ray_dirs[3 * i + 2];
    float nrm = sqrtf(dx * dx + dy * dy + dz * dz);
    float rx = dx / nrm, ry = dy / nrm, rz = dz / nrm;

    // sphere intersection
    float rcd = rx * cx + ry * cy + rz * cz;
    float c2  = cx * cx + cy * cy + cz * cz;
    float us  = rcd * rcd - (c2 - RADIUSV * RADIUSV);
    bool  mask_int = us > 0.0f;
    float s_sq = mask_int ? sqrtf(us) : 0.0f;
    float far_raw = mask_int ? fmaxf(s_sq - rcd, 0.0f) : 0.0f;
    float farv = fmaxf(far_raw, NEARV + EPSV);

    // per-ray factored MLP, packed 2 hidden units per f2:
    //   a_h(d) = cW[h] + d * rW[h];  logit = sum_h relu(a_h)*w2[h] + B2
    f2 rW[HDIM / 2], cW[HDIM / 2], w2[HDIM / 2];
    #pragma unroll
    for (int h = 0; h < HDIM / 2; ++h) {
        float4 wa = sW[2 * h], wb = sW[2 * h + 1];
        rW[h] = (f2){rx * wa.x + ry * wa.y + rz * wa.z,
                     rx * wb.x + ry * wb.y + rz * wb.z};
        cW[h] = (f2){cx * wa.x + cy * wa.y + cz * wa.z + wa.w,
                     cx * wb.x + cy * wb.y + cz * wb.z + wb.w};
        w2[h] = (f2){sW2[2 * h], sW2[2 * h + 1]};
    }
    const float B2 = sB2;
    const f2 z2 = (f2){0.0f, 0.0f};

    auto logit = [&](float d) -> float {
        f2 dv = (f2){d, d};
        f2 a0 = z2, a1 = z2, a2 = z2, a3 = z2;
        #pragma unroll
        for (int h = 0; h < HDIM / 2; h += 4) {
            f2 x0 = __builtin_elementwise_fma(dv, rW[h + 0], cW[h + 0]);
            f2 x1 = __builtin_elementwise_fma(dv, rW[h + 1], cW[h + 1]);
            f2 x2 = __builtin_elementwise_fma(dv, rW[h + 2], cW[h + 2]);
            f2 x3 = __builtin_elementwise_fma(dv, rW[h + 3], cW[h + 3]);
            a0 = __builtin_elementwise_fma(__builtin_elementwise_max(x0, z2), w2[h + 0], a0);
            a1 = __builtin_elementwise_fma(__builtin_elementwise_max(x1, z2), w2[h + 1], a1);
            a2 = __builtin_elementwise_fma(__builtin_elementwise_max(x2, z2), w2[h + 2], a2);
            a3 = __builtin_elementwise_fma(__builtin_elementwise_max(x3, z2), w2[h + 3], a3);
        }
        f2 aa = (a0 + a1) + (a2 + a3);
        return (aa.x + aa.y) + B2;
    };
    auto sigm = [](float x) -> float {   // fast sigmoid: v_exp + v_rcp
        float e = __expf(-x);
        return __builtin_amdgcn_rcpf(1.0f + e);
    };

    // coarse march: logits only (sign(sigmoid(x)-0.5) == sign(x))
    float l_prev = logit(NEARV);
    float d_prev = NEARV;
    const float l0 = l_prev;
    float d1v = 0.0f, l1v = 0.0f;

    bool found = false;
    float d_lo = 0.0f, l_lo = 0.0f, d_hi = 0.0f, l_hi = 0.0f;

    const float STEPC = 0.03225806451612903f;  // fl(1/31)
    #pragma unroll 2
    for (int s = 1; s < NSTEPS; ++s) {
        float t = (float)s * STEPC;
        float dd = NEARV * (1.0f - t) + farv * t;
        float ls = logit(dd);
        if (s == 1) { d1v = dd; l1v = ls; }
        if (!found && (l_prev < 0.0f) && (ls >= 0.0f)) {
            found = true;
            d_lo = d_prev; l_lo = l_prev;
            d_hi = dd;     l_hi = ls;
        }
        d_prev = dd; l_prev = ls;
    }
    if (!found) {  // reference: idx = argmax(all-false) = 0
        d_lo = NEARV; l_lo = l0;
        d_hi = d1v;   l_hi = l1v;
    }
    found = found && mask_int;

    // convert bracket logits to f = sigmoid - tau for the secant
    float f_lo = sigm(l_lo) - TAUV;
    float f_hi = sigm(l_hi) - TAUV;

    // secant refinement
    #pragma unroll 1
    for (int it = 0; it < NSECANT; ++it) {
        float den = f_hi - f_lo;
        den = (fabsf(den) < EPSV) ? EPSV : den;
        float dm = d_lo - f_lo * (d_hi - d_lo) * __builtin_amdgcn_rcpf(den);
        float fm = sigm(logit(dm)) - TAUV;
        bool neg = fm < 0.0f;
        d_lo = neg ? dm : d_lo;
        f_lo = neg ? fm : f_lo;
        d_hi = neg ? d_hi : dm;
        f_hi = neg ? f_hi : fm;
    }
    float den = f_hi - f_lo;
    den = (fabsf(den) < EPSV) ? EPSV : den;
    float d_mid = d_lo - f_lo * (d_hi - d_lo) * __builtin_amdgcn_rcpf(den);

    float d_pred = found ? d_mid : 0.0f;
    float occ_s = sigm(logit(d_pred));
    float occ_surf = found ? occ_s : 0.0f;

    out[i]     = d_pred;
    out[P + i] = occ_surf;
}

extern "C" void kernel_launch(void* const* d_in, const int* in_sizes, int n_in,
                              void* d_out, int out_size, void* d_ws, size_t ws_size,
                              hipStream_t stream) {
    const float* cam_loc  = (const float*)d_in[0];
    const float* ray_dirs = (const float*)d_in[1];
    const float* W1       = (const float*)d_in[2];
    const float* b1       = (const float*)d_in[3];
    const float* W2       = (const float*)d_in[4];
    const float* b2       = (const float*)d_in[5];
    float* out = (float*)d_out;

    const int P = in_sizes[1] / 3;
    const int block = 256;
    const int grid = (P + block - 1) / block;
    unisurf_kernel<<<grid, block, 0, stream>>>(cam_loc, ray_dirs, W1, b1, W2, b2, out, P);
}